// Round 12
// baseline (132.778 us; speedup 1.0000x reference)
//
#include <hip/hip_runtime.h>
#include <hip/hip_fp16.h>

typedef float    f32x4 __attribute__((ext_vector_type(4)));
typedef _Float16 f16x8 __attribute__((ext_vector_type(8)));

#define BF_DIM 1024
#define BF_STAGES 10

// f16 (cos,sin) tables: 4 B/pair, 2 KB/stage, 20 KB total -> L1-resident.
// Per stage, lane l's 8 needed pairs are packed contiguously at pairs [l*8..l*8+7]:
//   stages 0-3: pos = k (natural order IS lane-contiguous for the reg layout)
//   stages 4-7: k = hi2*128 + j*16 + lo4 -> pos = (hi2*16+lo4)*8 + j   (layout B)
//   stages 8-9: k = g*256 + lane*4 + c   -> pos = lane*8 + g*4 + c     (layout C)
__global__ void bf_fill_cs(const float* __restrict__ angles, unsigned* __restrict__ cs, int n) {
    int i = blockIdx.x * blockDim.x + threadIdx.x;
    if (i >= n) return;
    int s = i >> 9, k = i & 511;
    float a = angles[i];
    float sv, cv;
    sincosf(a, &sv, &cv);
    int pos;
    if (s >= 4 && s < 8) {
        int hi2 = k >> 7, j = (k >> 4) & 7, lo4 = k & 15;
        pos = ((hi2 << 4) | lo4) * 8 + j;
    } else if (s >= 8) {
        pos = ((k & 255) >> 2) * 8 + (k >> 8) * 4 + (k & 3);
    } else {
        pos = k;
    }
    unsigned hc = __half_as_ushort(__float2half_rn(cv));
    unsigned hs = __half_as_ushort(__float2half_rn(sv));
    cs[s * 512 + pos] = (hs << 16) | hc;   // low16 = cos, high16 = sin (LE)
}

#define ROT(vi, vj, c, s) do { float _t = fmaf(-(s), (vj), (c)*(vi)); \
                               (vj) = fmaf((s), (vi), (c)*(vj)); (vi) = _t; } while (0)

// Expand one f16x8 (4 cos/sin pairs) into two f32x4 coeff vecs (c0,s0,c1,s1).
#define EXP(t, ca, cb) do { \
    ca = (f32x4){(float)(t)[0], (float)(t)[1], (float)(t)[2], (float)(t)[3]}; \
    cb = (f32x4){(float)(t)[4], (float)(t)[5], (float)(t)[6], (float)(t)[7]}; } while (0)

// Half-stage ops on a pair of data vecs with 2 coeff vecs (4 pairs).
#define H_EVEN(P, Q, c0, c1) do { \
    ROT(P.x, P.y, c0.x, c0.y); ROT(P.z, P.w, c0.z, c0.w); \
    ROT(Q.x, Q.y, c1.x, c1.y); ROT(Q.z, Q.w, c1.z, c1.w); } while (0)
#define H_ODD(P, Q, c0, c1) do { \
    ROT(P.x, P.z, c0.x, c0.y); ROT(P.y, P.w, c0.z, c0.w); \
    ROT(Q.x, Q.z, c1.x, c1.y); ROT(Q.y, Q.w, c1.z, c1.w); } while (0)
#define H_PAIR(P, Q, c0, c1) do { \
    ROT(P.x, Q.x, c0.x, c0.y); ROT(P.y, Q.y, c0.z, c0.w); \
    ROT(P.z, Q.z, c1.x, c1.y); ROT(P.w, Q.w, c1.z, c1.w); } while (0)

// One full stage = two in-loop f16x8 L1-hit loads (r9 scheme); expand lazily.
#define DO_STAGE(HOP, sidx, X0, X1, X2, X3, Y0, Y1, Y2, Y3) do { \
    f16x8 _t0 = TH[(sidx) * 128 + lane * 2], _t1 = TH[(sidx) * 128 + lane * 2 + 1]; \
    f32x4 _c0, _c1; \
    EXP(_t0, _c0, _c1); \
    HOP(X0, X1, _c0, _c1); HOP(Y0, Y1, _c0, _c1); \
    EXP(_t1, _c0, _c1); \
    HOP(X2, X3, _c0, _c1); HOP(Y2, Y3, _c0, _c1); } while (0)

// Round-12 = r9 (124us best: R=2, in-loop f16 L1-resident tables, two
// stride-20 wave-private slabs, zero barriers) + ONE-PAIR-DEEP PREFETCH.
// r9's 8 data loads were issued at iteration top and consumed immediately:
// under BW saturation their queueing latency (~2-4k cyc) was fully exposed
// each iteration (~30% memory-pipe idle by cycle accounting). Prefetch
// issues pair i+1's loads right after consuming pair i, BEFORE tables and
// stores, so at the next consume they are the OLDEST vmcnt entries and the
// wait resolves without draining younger table loads / stores.
// VGPR: 32 prefetch + 32 data + ~16 transient + ~10 addr ~ 90 <= 128 budget
// from __launch_bounds__(256,2) (r2 evidence). LDS 40KB -> 4 blocks/CU.
__global__ __launch_bounds__(256, 2) void bf_butterfly(const float* __restrict__ x,
                                                       const f16x8* __restrict__ TH,
                                                       float* __restrict__ out,
                                                       int n_rows, int pair_stride) {
    __shared__ __align__(16) float lds[4 * 2560];  // 4 waves * 2 rows * 20*64 words = 40 KB
    const int lane = threadIdx.x & 63;
    const int wv   = threadIdx.x >> 6;
    float* LA = lds + wv * 2560;   // row 0 slab
    float* LB = LA + 1280;         // row 1 slab

    const int wb = lane * 20;                         // layout A base
    const int rb = (lane >> 4) * 320 + (lane & 15);   // layout B base
    const int cb = (lane >> 2) * 20 + (lane & 3) * 4; // layout C base

    const int n_pairs = (n_rows + 1) >> 1;
    int pair = blockIdx.x * 4 + wv;
    if (pair >= n_pairs) return;

    // ---- prime the pipeline: prefetch pair's two rows (clamped)
    {
        int r0 = pair * 2;
        int r1 = (r0 + 1 < n_rows) ? r0 + 1 : r0;
        const float* xr0 = x + (long long)r0 * BF_DIM + lane * 16;
        const float* xr1 = x + (long long)r1 * BF_DIM + lane * 16;
        // assigned below via first consume
        // (loads issued here)
        // P registers:
        // fallthrough
        // -- declared outside the block
        ;
    }
    f32x4 P0, P1, P2, P3, Q0, Q1, Q2, Q3;
    {
        int r0 = pair * 2;
        int r1 = (r0 + 1 < n_rows) ? r0 + 1 : r0;
        const float* xr0 = x + (long long)r0 * BF_DIM + lane * 16;
        const float* xr1 = x + (long long)r1 * BF_DIM + lane * 16;
        P0 = __builtin_nontemporal_load((const f32x4*)(xr0 + 0));
        P1 = __builtin_nontemporal_load((const f32x4*)(xr0 + 4));
        P2 = __builtin_nontemporal_load((const f32x4*)(xr0 + 8));
        P3 = __builtin_nontemporal_load((const f32x4*)(xr0 + 12));
        Q0 = __builtin_nontemporal_load((const f32x4*)(xr1 + 0));
        Q1 = __builtin_nontemporal_load((const f32x4*)(xr1 + 4));
        Q2 = __builtin_nontemporal_load((const f32x4*)(xr1 + 8));
        Q3 = __builtin_nontemporal_load((const f32x4*)(xr1 + 12));
    }

#pragma unroll 1
    while (true) {
        const int r0 = pair * 2;
        const int r1 = r0 + 1;
        const bool has1 = (r1 < n_rows);

        // ---- consume prefetched pair (wait hits only the OLDEST vmcnt entries)
        f32x4 U0 = P0, U1 = P1, U2 = P2, U3 = P3;
        f32x4 W0 = Q0, W1 = Q1, W2 = Q2, W3 = Q3;

        // ---- issue next pair's loads NOW (before tables and stores)
        const int nxt = pair + pair_stride;
        const bool more = nxt < n_pairs;
        {
            int pr = more ? nxt : pair;
            int pr0 = pr * 2;
            int pr1 = (pr0 + 1 < n_rows) ? pr0 + 1 : pr0;
            const float* xn0 = x + (long long)pr0 * BF_DIM + lane * 16;
            const float* xn1 = x + (long long)pr1 * BF_DIM + lane * 16;
            P0 = __builtin_nontemporal_load((const f32x4*)(xn0 + 0));
            P1 = __builtin_nontemporal_load((const f32x4*)(xn0 + 4));
            P2 = __builtin_nontemporal_load((const f32x4*)(xn0 + 8));
            P3 = __builtin_nontemporal_load((const f32x4*)(xn0 + 12));
            Q0 = __builtin_nontemporal_load((const f32x4*)(xn1 + 0));
            Q1 = __builtin_nontemporal_load((const f32x4*)(xn1 + 4));
            Q2 = __builtin_nontemporal_load((const f32x4*)(xn1 + 8));
            Q3 = __builtin_nontemporal_load((const f32x4*)(xn1 + 12));
        }

        // ---- stages 0-3 (layout A, in regs)
        DO_STAGE(H_EVEN, 0, U0, U1, U2, U3, W0, W1, W2, W3);
        DO_STAGE(H_ODD,  1, U0, U1, U2, U3, W0, W1, W2, W3);
        DO_STAGE(H_PAIR, 2, U0, U1, U2, U3, W0, W1, W2, W3);
        DO_STAGE(H_PAIR, 3, U0, U2, U1, U3, W0, W2, W1, W3);  // pairs (0,2),(1,3)

        // ---- transpose 1: write layout A (b128), read layout B (b32); wave-private
        *(f32x4*)(LA + wb + 0)  = U0;
        *(f32x4*)(LA + wb + 4)  = U1;
        *(f32x4*)(LA + wb + 8)  = U2;
        *(f32x4*)(LA + wb + 12) = U3;
        *(f32x4*)(LB + wb + 0)  = W0;
        *(f32x4*)(LB + wb + 4)  = W1;
        *(f32x4*)(LB + wb + 8)  = W2;
        *(f32x4*)(LB + wb + 12) = W3;
        U0.x = LA[rb + 0 * 20];  U0.y = LA[rb + 1 * 20];  U0.z = LA[rb + 2 * 20];  U0.w = LA[rb + 3 * 20];
        U1.x = LA[rb + 4 * 20];  U1.y = LA[rb + 5 * 20];  U1.z = LA[rb + 6 * 20];  U1.w = LA[rb + 7 * 20];
        U2.x = LA[rb + 8 * 20];  U2.y = LA[rb + 9 * 20];  U2.z = LA[rb + 10 * 20]; U2.w = LA[rb + 11 * 20];
        U3.x = LA[rb + 12 * 20]; U3.y = LA[rb + 13 * 20]; U3.z = LA[rb + 14 * 20]; U3.w = LA[rb + 15 * 20];
        W0.x = LB[rb + 0 * 20];  W0.y = LB[rb + 1 * 20];  W0.z = LB[rb + 2 * 20];  W0.w = LB[rb + 3 * 20];
        W1.x = LB[rb + 4 * 20];  W1.y = LB[rb + 5 * 20];  W1.z = LB[rb + 6 * 20];  W1.w = LB[rb + 7 * 20];
        W2.x = LB[rb + 8 * 20];  W2.y = LB[rb + 9 * 20];  W2.z = LB[rb + 10 * 20]; W2.w = LB[rb + 11 * 20];
        W3.x = LB[rb + 12 * 20]; W3.y = LB[rb + 13 * 20]; W3.z = LB[rb + 14 * 20]; W3.w = LB[rb + 15 * 20];

        // ---- stages 4-7 (layout B, in regs)
        DO_STAGE(H_EVEN, 4, U0, U1, U2, U3, W0, W1, W2, W3);
        DO_STAGE(H_ODD,  5, U0, U1, U2, U3, W0, W1, W2, W3);
        DO_STAGE(H_PAIR, 6, U0, U1, U2, U3, W0, W1, W2, W3);
        DO_STAGE(H_PAIR, 7, U0, U2, U1, U3, W0, W2, W1, W3);

        // ---- transpose 2: write layout B back (b32), read layout C (b128)
        LA[rb + 0 * 20]  = U0.x; LA[rb + 1 * 20]  = U0.y; LA[rb + 2 * 20]  = U0.z; LA[rb + 3 * 20]  = U0.w;
        LA[rb + 4 * 20]  = U1.x; LA[rb + 5 * 20]  = U1.y; LA[rb + 6 * 20]  = U1.z; LA[rb + 7 * 20]  = U1.w;
        LA[rb + 8 * 20]  = U2.x; LA[rb + 9 * 20]  = U2.y; LA[rb + 10 * 20] = U2.z; LA[rb + 11 * 20] = U2.w;
        LA[rb + 12 * 20] = U3.x; LA[rb + 13 * 20] = U3.y; LA[rb + 14 * 20] = U3.z; LA[rb + 15 * 20] = U3.w;
        LB[rb + 0 * 20]  = W0.x; LB[rb + 1 * 20]  = W0.y; LB[rb + 2 * 20]  = W0.z; LB[rb + 3 * 20]  = W0.w;
        LB[rb + 4 * 20]  = W1.x; LB[rb + 5 * 20]  = W1.y; LB[rb + 6 * 20]  = W1.z; LB[rb + 7 * 20]  = W1.w;
        LB[rb + 8 * 20]  = W2.x; LB[rb + 9 * 20]  = W2.y; LB[rb + 10 * 20] = W2.z; LB[rb + 11 * 20] = W2.w;
        LB[rb + 12 * 20] = W3.x; LB[rb + 13 * 20] = W3.y; LB[rb + 14 * 20] = W3.z; LB[rb + 15 * 20] = W3.w;
        U0 = *(const f32x4*)(LA + cb);
        U1 = *(const f32x4*)(LA + cb + 320);
        U2 = *(const f32x4*)(LA + cb + 640);
        U3 = *(const f32x4*)(LA + cb + 960);
        W0 = *(const f32x4*)(LB + cb);
        W1 = *(const f32x4*)(LB + cb + 320);
        W2 = *(const f32x4*)(LB + cb + 640);
        W3 = *(const f32x4*)(LB + cb + 960);

        // ---- stages 8-9 (layout C, in regs)
        DO_STAGE(H_PAIR, 8, U0, U1, U2, U3, W0, W1, W2, W3);
        DO_STAGE(H_PAIR, 9, U0, U2, U1, U3, W0, W2, W1, W3);

        float* o0 = out + (long long)r0 * BF_DIM;
        __builtin_nontemporal_store(U0, (f32x4*)(o0 + lane * 4));
        __builtin_nontemporal_store(U1, (f32x4*)(o0 + 256 + lane * 4));
        __builtin_nontemporal_store(U2, (f32x4*)(o0 + 512 + lane * 4));
        __builtin_nontemporal_store(U3, (f32x4*)(o0 + 768 + lane * 4));
        if (has1) {
            float* o1 = out + (long long)r1 * BF_DIM;
            __builtin_nontemporal_store(W0, (f32x4*)(o1 + lane * 4));
            __builtin_nontemporal_store(W1, (f32x4*)(o1 + 256 + lane * 4));
            __builtin_nontemporal_store(W2, (f32x4*)(o1 + 512 + lane * 4));
            __builtin_nontemporal_store(W3, (f32x4*)(o1 + 768 + lane * 4));
        }

        if (!more) break;
        pair = nxt;
    }
}

extern "C" void kernel_launch(void* const* d_in, const int* in_sizes, int n_in,
                              void* d_out, int out_size, void* d_ws, size_t ws_size,
                              hipStream_t stream) {
    const float* x      = (const float*)d_in[0];
    const float* angles = (const float*)d_in[1];
    float*       out    = (float*)d_out;
    unsigned*    cs     = (unsigned*)d_ws;  // 10*512*4 = 20480 bytes

    const int ncs = BF_STAGES * (BF_DIM / 2);
    bf_fill_cs<<<(ncs + 255) / 256, 256, 0, stream>>>(angles, cs, ncs);

    const int rows    = in_sizes[0] / BF_DIM;
    const int n_pairs = (rows + 1) / 2;
    int blocks = (n_pairs + 3) / 4;
    if (blocks > 1024) blocks = 1024;     // 4 blocks/CU (40KB LDS) resident; 8 pair-iters/wave
    const int pair_stride = blocks * 4;   // total waves
    bf_butterfly<<<blocks, 256, 0, stream>>>(x, (const f16x8*)cs, out, rows, pair_stride);
}

// Round 13
// 125.033 us; speedup vs baseline: 1.0619x; 1.0619x over previous
//
#include <hip/hip_runtime.h>
#include <hip/hip_fp16.h>

typedef float    f32x4 __attribute__((ext_vector_type(4)));
typedef _Float16 f16x8 __attribute__((ext_vector_type(8)));

#define BF_DIM 1024
#define BF_STAGES 10

// f16 (cos,sin) tables: 4 B/pair, 2 KB/stage, 20 KB total -> L1-resident,
// shared by every block on a CU (same global addresses).
// Per stage, lane l's 8 needed pairs are packed contiguously at pairs [l*8..l*8+7]:
//   stages 0-3: pos = k (natural order IS lane-contiguous for the reg layout)
//   stages 4-7: k = hi2*128 + j*16 + lo4 -> pos = (hi2*16+lo4)*8 + j   (layout B)
//   stages 8-9: k = g*256 + lane*4 + c   -> pos = lane*8 + g*4 + c     (layout C)
__global__ void bf_fill_cs(const float* __restrict__ angles, unsigned* __restrict__ cs, int n) {
    int i = blockIdx.x * blockDim.x + threadIdx.x;
    if (i >= n) return;
    int s = i >> 9, k = i & 511;
    float a = angles[i];
    float sv, cv;
    sincosf(a, &sv, &cv);
    int pos;
    if (s >= 4 && s < 8) {
        int hi2 = k >> 7, j = (k >> 4) & 7, lo4 = k & 15;
        pos = ((hi2 << 4) | lo4) * 8 + j;
    } else if (s >= 8) {
        pos = ((k & 255) >> 2) * 8 + (k >> 8) * 4 + (k & 3);
    } else {
        pos = k;
    }
    unsigned hc = __half_as_ushort(__float2half_rn(cv));
    unsigned hs = __half_as_ushort(__float2half_rn(sv));
    cs[s * 512 + pos] = (hs << 16) | hc;   // low16 = cos, high16 = sin (LE)
}

#define ROT(vi, vj, c, s) do { float _t = fmaf(-(s), (vj), (c)*(vi)); \
                               (vj) = fmaf((s), (vi), (c)*(vj)); (vi) = _t; } while (0)

// Expand one f16x8 (4 cos/sin pairs) into two f32x4 coeff vecs (c0,s0,c1,s1).
#define EXP(t, ca, cb) do { \
    ca = (f32x4){(float)(t)[0], (float)(t)[1], (float)(t)[2], (float)(t)[3]}; \
    cb = (f32x4){(float)(t)[4], (float)(t)[5], (float)(t)[6], (float)(t)[7]}; } while (0)

// Half-stage ops on a pair of data vecs with 2 coeff vecs (4 pairs).
#define H_EVEN(P, Q, c0, c1) do { \
    ROT(P.x, P.y, c0.x, c0.y); ROT(P.z, P.w, c0.z, c0.w); \
    ROT(Q.x, Q.y, c1.x, c1.y); ROT(Q.z, Q.w, c1.z, c1.w); } while (0)
#define H_ODD(P, Q, c0, c1) do { \
    ROT(P.x, P.z, c0.x, c0.y); ROT(P.y, P.w, c0.z, c0.w); \
    ROT(Q.x, Q.z, c1.x, c1.y); ROT(Q.y, Q.w, c1.z, c1.w); } while (0)
#define H_PAIR(P, Q, c0, c1) do { \
    ROT(P.x, Q.x, c0.x, c0.y); ROT(P.y, Q.y, c0.z, c0.w); \
    ROT(P.z, Q.z, c1.x, c1.y); ROT(P.w, Q.w, c1.z, c1.w); } while (0)

// One full stage = two in-loop f16x8 L1-hit loads (r9 scheme); expand lazily.
#define DO_STAGE(HOP, sidx, X0, X1, X2, X3, Y0, Y1, Y2, Y3) do { \
    f16x8 _t0 = TH[(sidx) * 128 + lane * 2], _t1 = TH[(sidx) * 128 + lane * 2 + 1]; \
    f32x4 _c0, _c1; \
    EXP(_t0, _c0, _c1); \
    HOP(X0, X1, _c0, _c1); HOP(Y0, Y1, _c0, _c1); \
    EXP(_t1, _c0, _c1); \
    HOP(X2, X3, _c0, _c1); HOP(Y2, Y3, _c0, _c1); } while (0)

// Round-13 = r9 (124us best: R=2, in-loop f16 L1-resident tables, zero
// barriers) with LDS HALVED to re-enable 8 blocks/CU = 32 waves/CU:
// ONE 5 KB stride-20 slab per wave, row0 then row1 passed through it
// sequentially. Same-wave DS ops are pipe-ordered (in-order LDS), and U's
// transpose reads are issued before W's writes -> correct with no barrier.
// Rationale: r6/r8's 32-wave attempts ran 40KB f32 tables (> 32KB L1,
// thrash at high wave rate); r9's f16 table is 20KB, L1-FIT, and shared by
// all blocks on a CU -> occupancy can finally buy memory parallelism.
// Plain __launch_bounds__(256): allocator targets its preferred 64-VGPR
// point (r2/r3/r5 evidence); live set ~ 32 data + 8 coeff + addr ~ 55.
__global__ __launch_bounds__(256) void bf_butterfly(const float* __restrict__ x,
                                                    const f16x8* __restrict__ TH,
                                                    float* __restrict__ out,
                                                    int n_rows, int pair_stride) {
    __shared__ __align__(16) float lds[4 * 1280];  // 4 waves * 1280 words = 20 KB
    const int lane = threadIdx.x & 63;
    const int wv   = threadIdx.x >> 6;
    float* L = lds + wv * 1280;

    const int wb = lane * 20;                         // layout A base
    const int rb = (lane >> 4) * 320 + (lane & 15);   // layout B base
    const int cb = (lane >> 2) * 20 + (lane & 3) * 4; // layout C base

    const int n_pairs = (n_rows + 1) >> 1;

#pragma unroll 1
    for (int pair = blockIdx.x * 4 + wv; pair < n_pairs; pair += pair_stride) {
        const int r0 = pair * 2;
        const int r1 = r0 + 1;
        const bool has1 = (r1 < n_rows);

        const float* xr0 = x + (long long)r0 * BF_DIM + lane * 16;
        const float* xr1 = x + (long long)(has1 ? r1 : r0) * BF_DIM + lane * 16;
        f32x4 U0 = __builtin_nontemporal_load((const f32x4*)(xr0 + 0));
        f32x4 U1 = __builtin_nontemporal_load((const f32x4*)(xr0 + 4));
        f32x4 U2 = __builtin_nontemporal_load((const f32x4*)(xr0 + 8));
        f32x4 U3 = __builtin_nontemporal_load((const f32x4*)(xr0 + 12));
        f32x4 W0 = __builtin_nontemporal_load((const f32x4*)(xr1 + 0));
        f32x4 W1 = __builtin_nontemporal_load((const f32x4*)(xr1 + 4));
        f32x4 W2 = __builtin_nontemporal_load((const f32x4*)(xr1 + 8));
        f32x4 W3 = __builtin_nontemporal_load((const f32x4*)(xr1 + 12));

        // ---- stages 0-3 (layout A, in regs; tables shared by both rows)
        DO_STAGE(H_EVEN, 0, U0, U1, U2, U3, W0, W1, W2, W3);
        DO_STAGE(H_ODD,  1, U0, U1, U2, U3, W0, W1, W2, W3);
        DO_STAGE(H_PAIR, 2, U0, U1, U2, U3, W0, W1, W2, W3);
        DO_STAGE(H_PAIR, 3, U0, U2, U1, U3, W0, W2, W1, W3);  // pairs (0,2),(1,3)

        // ---- transpose 1 through the single slab, row0 then row1.
        // In-order DS pipe: U's b32 reads are issued (and complete) before
        // W's b128 writes touch the same words -> no barrier needed.
        *(f32x4*)(L + wb + 0)  = U0;
        *(f32x4*)(L + wb + 4)  = U1;
        *(f32x4*)(L + wb + 8)  = U2;
        *(f32x4*)(L + wb + 12) = U3;
        U0.x = L[rb + 0 * 20];  U0.y = L[rb + 1 * 20];  U0.z = L[rb + 2 * 20];  U0.w = L[rb + 3 * 20];
        U1.x = L[rb + 4 * 20];  U1.y = L[rb + 5 * 20];  U1.z = L[rb + 6 * 20];  U1.w = L[rb + 7 * 20];
        U2.x = L[rb + 8 * 20];  U2.y = L[rb + 9 * 20];  U2.z = L[rb + 10 * 20]; U2.w = L[rb + 11 * 20];
        U3.x = L[rb + 12 * 20]; U3.y = L[rb + 13 * 20]; U3.z = L[rb + 14 * 20]; U3.w = L[rb + 15 * 20];
        *(f32x4*)(L + wb + 0)  = W0;
        *(f32x4*)(L + wb + 4)  = W1;
        *(f32x4*)(L + wb + 8)  = W2;
        *(f32x4*)(L + wb + 12) = W3;
        W0.x = L[rb + 0 * 20];  W0.y = L[rb + 1 * 20];  W0.z = L[rb + 2 * 20];  W0.w = L[rb + 3 * 20];
        W1.x = L[rb + 4 * 20];  W1.y = L[rb + 5 * 20];  W1.z = L[rb + 6 * 20];  W1.w = L[rb + 7 * 20];
        W2.x = L[rb + 8 * 20];  W2.y = L[rb + 9 * 20];  W2.z = L[rb + 10 * 20]; W2.w = L[rb + 11 * 20];
        W3.x = L[rb + 12 * 20]; W3.y = L[rb + 13 * 20]; W3.z = L[rb + 14 * 20]; W3.w = L[rb + 15 * 20];

        // ---- stages 4-7 (layout B, in regs)
        DO_STAGE(H_EVEN, 4, U0, U1, U2, U3, W0, W1, W2, W3);
        DO_STAGE(H_ODD,  5, U0, U1, U2, U3, W0, W1, W2, W3);
        DO_STAGE(H_PAIR, 6, U0, U1, U2, U3, W0, W1, W2, W3);
        DO_STAGE(H_PAIR, 7, U0, U2, U1, U3, W0, W2, W1, W3);

        // ---- transpose 2 through the single slab, row0 then row1.
        L[rb + 0 * 20]  = U0.x; L[rb + 1 * 20]  = U0.y; L[rb + 2 * 20]  = U0.z; L[rb + 3 * 20]  = U0.w;
        L[rb + 4 * 20]  = U1.x; L[rb + 5 * 20]  = U1.y; L[rb + 6 * 20]  = U1.z; L[rb + 7 * 20]  = U1.w;
        L[rb + 8 * 20]  = U2.x; L[rb + 9 * 20]  = U2.y; L[rb + 10 * 20] = U2.z; L[rb + 11 * 20] = U2.w;
        L[rb + 12 * 20] = U3.x; L[rb + 13 * 20] = U3.y; L[rb + 14 * 20] = U3.z; L[rb + 15 * 20] = U3.w;
        U0 = *(const f32x4*)(L + cb);
        U1 = *(const f32x4*)(L + cb + 320);
        U2 = *(const f32x4*)(L + cb + 640);
        U3 = *(const f32x4*)(L + cb + 960);
        L[rb + 0 * 20]  = W0.x; L[rb + 1 * 20]  = W0.y; L[rb + 2 * 20]  = W0.z; L[rb + 3 * 20]  = W0.w;
        L[rb + 4 * 20]  = W1.x; L[rb + 5 * 20]  = W1.y; L[rb + 6 * 20]  = W1.z; L[rb + 7 * 20]  = W1.w;
        L[rb + 8 * 20]  = W2.x; L[rb + 9 * 20]  = W2.y; L[rb + 10 * 20] = W2.z; L[rb + 11 * 20] = W2.w;
        L[rb + 12 * 20] = W3.x; L[rb + 13 * 20] = W3.y; L[rb + 14 * 20] = W3.z; L[rb + 15 * 20] = W3.w;
        W0 = *(const f32x4*)(L + cb);
        W1 = *(const f32x4*)(L + cb + 320);
        W2 = *(const f32x4*)(L + cb + 640);
        W3 = *(const f32x4*)(L + cb + 960);

        // ---- stages 8-9 (layout C, in regs)
        DO_STAGE(H_PAIR, 8, U0, U1, U2, U3, W0, W1, W2, W3);
        DO_STAGE(H_PAIR, 9, U0, U2, U1, U3, W0, W2, W1, W3);

        float* o0 = out + (long long)r0 * BF_DIM;
        __builtin_nontemporal_store(U0, (f32x4*)(o0 + lane * 4));
        __builtin_nontemporal_store(U1, (f32x4*)(o0 + 256 + lane * 4));
        __builtin_nontemporal_store(U2, (f32x4*)(o0 + 512 + lane * 4));
        __builtin_nontemporal_store(U3, (f32x4*)(o0 + 768 + lane * 4));
        if (has1) {
            float* o1 = out + (long long)r1 * BF_DIM;
            __builtin_nontemporal_store(W0, (f32x4*)(o1 + lane * 4));
            __builtin_nontemporal_store(W1, (f32x4*)(o1 + 256 + lane * 4));
            __builtin_nontemporal_store(W2, (f32x4*)(o1 + 512 + lane * 4));
            __builtin_nontemporal_store(W3, (f32x4*)(o1 + 768 + lane * 4));
        }
    }
}

extern "C" void kernel_launch(void* const* d_in, const int* in_sizes, int n_in,
                              void* d_out, int out_size, void* d_ws, size_t ws_size,
                              hipStream_t stream) {
    const float* x      = (const float*)d_in[0];
    const float* angles = (const float*)d_in[1];
    float*       out    = (float*)d_out;
    unsigned*    cs     = (unsigned*)d_ws;  // 10*512*4 = 20480 bytes

    const int ncs = BF_STAGES * (BF_DIM / 2);
    bf_fill_cs<<<(ncs + 255) / 256, 256, 0, stream>>>(angles, cs, ncs);

    const int rows    = in_sizes[0] / BF_DIM;
    const int n_pairs = (rows + 1) / 2;
    int blocks = (n_pairs + 3) / 4;
    if (blocks > 2048) blocks = 2048;     // 8 blocks/CU (20KB LDS) -> 32 waves/CU
    const int pair_stride = blocks * 4;   // total waves
    bf_butterfly<<<blocks, 256, 0, stream>>>(x, (const f16x8*)cs, out, rows, pair_stride);
}

// Round 14
// 106.473 us; speedup vs baseline: 1.2471x; 1.1743x over previous
//
#include <hip/hip_runtime.h>
#include <hip/hip_fp16.h>

typedef float    f32x4 __attribute__((ext_vector_type(4)));
typedef _Float16 f16x8 __attribute__((ext_vector_type(8)));

#define BF_DIM 1024
#define BF_STAGES 10

// f16 (cos,sin) tables: 4 B/pair, 2 KB/stage, 20 KB total -> L1-resident,
// shared by every block on a CU (same global addresses).
// Per stage, lane l's 8 needed pairs are packed contiguously at pairs [l*8..l*8+7]:
//   stages 0-3: pos = k (natural order IS lane-contiguous for the reg layout)
//   stages 4-7: k = hi2*128 + j*16 + lo4 -> pos = (hi2*16+lo4)*8 + j   (layout B)
//   stages 8-9: k = g*256 + lane*4 + c   -> pos = lane*8 + g*4 + c     (layout C)
__global__ void bf_fill_cs(const float* __restrict__ angles, unsigned* __restrict__ cs, int n) {
    int i = blockIdx.x * blockDim.x + threadIdx.x;
    if (i >= n) return;
    int s = i >> 9, k = i & 511;
    float a = angles[i];
    float sv, cv;
    sincosf(a, &sv, &cv);
    int pos;
    if (s >= 4 && s < 8) {
        int hi2 = k >> 7, j = (k >> 4) & 7, lo4 = k & 15;
        pos = ((hi2 << 4) | lo4) * 8 + j;
    } else if (s >= 8) {
        pos = ((k & 255) >> 2) * 8 + (k >> 8) * 4 + (k & 3);
    } else {
        pos = k;
    }
    unsigned hc = __half_as_ushort(__float2half_rn(cv));
    unsigned hs = __half_as_ushort(__float2half_rn(sv));
    cs[s * 512 + pos] = (hs << 16) | hc;   // low16 = cos, high16 = sin (LE)
}

#define ROT(vi, vj, c, s) do { float _t = fmaf(-(s), (vj), (c)*(vi)); \
                               (vj) = fmaf((s), (vi), (c)*(vj)); (vi) = _t; } while (0)

// Expand one f16x8 (4 cos/sin pairs) into two f32x4 coeff vecs (c0,s0,c1,s1).
#define EXP(t, ca, cb) do { \
    ca = (f32x4){(float)(t)[0], (float)(t)[1], (float)(t)[2], (float)(t)[3]}; \
    cb = (f32x4){(float)(t)[4], (float)(t)[5], (float)(t)[6], (float)(t)[7]}; } while (0)

// Half-stage ops on a pair of data vecs with 2 coeff vecs (4 pairs).
#define H_EVEN(P, Q, c0, c1) do { \
    ROT(P.x, P.y, c0.x, c0.y); ROT(P.z, P.w, c0.z, c0.w); \
    ROT(Q.x, Q.y, c1.x, c1.y); ROT(Q.z, Q.w, c1.z, c1.w); } while (0)
#define H_ODD(P, Q, c0, c1) do { \
    ROT(P.x, P.z, c0.x, c0.y); ROT(P.y, P.w, c0.z, c0.w); \
    ROT(Q.x, Q.z, c1.x, c1.y); ROT(Q.y, Q.w, c1.z, c1.w); } while (0)
#define H_PAIR(P, Q, c0, c1) do { \
    ROT(P.x, Q.x, c0.x, c0.y); ROT(P.y, Q.y, c0.z, c0.w); \
    ROT(P.z, Q.z, c1.x, c1.y); ROT(P.w, Q.w, c1.z, c1.w); } while (0)

// One full stage = two in-loop f16x8 L1-hit loads (r9 scheme); expand lazily.
#define DO_STAGE(HOP, sidx, X0, X1, X2, X3, Y0, Y1, Y2, Y3) do { \
    f16x8 _t0 = TH[(sidx) * 128 + lane * 2], _t1 = TH[(sidx) * 128 + lane * 2 + 1]; \
    f32x4 _c0, _c1; \
    EXP(_t0, _c0, _c1); \
    HOP(X0, X1, _c0, _c1); HOP(Y0, Y1, _c0, _c1); \
    EXP(_t1, _c0, _c1); \
    HOP(X2, X3, _c0, _c1); HOP(Y2, Y3, _c0, _c1); } while (0)

// Round-14 = r13 (125us: R=2, f16 L1-resident tables, single 5KB slab,
// 8 blocks/CU = 32 waves/CU, zero barriers) with ONE change: the nt
// (nontemporal) modifier REMOVED from all data loads/stores. nt has been on
// every kernel since r3 and never A/B'd; the copy ceiling (6.3 TB/s) and the
// harness fill (7.0 TB/s) are both measured with PLAIN accesses. Suspected
// flat BW tax from nt's L2-bypass write path = the 12-round 124us plateau.
__global__ __launch_bounds__(256) void bf_butterfly(const float* __restrict__ x,
                                                    const f16x8* __restrict__ TH,
                                                    float* __restrict__ out,
                                                    int n_rows, int pair_stride) {
    __shared__ __align__(16) float lds[4 * 1280];  // 4 waves * 1280 words = 20 KB
    const int lane = threadIdx.x & 63;
    const int wv   = threadIdx.x >> 6;
    float* L = lds + wv * 1280;

    const int wb = lane * 20;                         // layout A base
    const int rb = (lane >> 4) * 320 + (lane & 15);   // layout B base
    const int cb = (lane >> 2) * 20 + (lane & 3) * 4; // layout C base

    const int n_pairs = (n_rows + 1) >> 1;

#pragma unroll 1
    for (int pair = blockIdx.x * 4 + wv; pair < n_pairs; pair += pair_stride) {
        const int r0 = pair * 2;
        const int r1 = r0 + 1;
        const bool has1 = (r1 < n_rows);

        const float* xr0 = x + (long long)r0 * BF_DIM + lane * 16;
        const float* xr1 = x + (long long)(has1 ? r1 : r0) * BF_DIM + lane * 16;
        f32x4 U0 = *(const f32x4*)(xr0 + 0);
        f32x4 U1 = *(const f32x4*)(xr0 + 4);
        f32x4 U2 = *(const f32x4*)(xr0 + 8);
        f32x4 U3 = *(const f32x4*)(xr0 + 12);
        f32x4 W0 = *(const f32x4*)(xr1 + 0);
        f32x4 W1 = *(const f32x4*)(xr1 + 4);
        f32x4 W2 = *(const f32x4*)(xr1 + 8);
        f32x4 W3 = *(const f32x4*)(xr1 + 12);

        // ---- stages 0-3 (layout A, in regs; tables shared by both rows)
        DO_STAGE(H_EVEN, 0, U0, U1, U2, U3, W0, W1, W2, W3);
        DO_STAGE(H_ODD,  1, U0, U1, U2, U3, W0, W1, W2, W3);
        DO_STAGE(H_PAIR, 2, U0, U1, U2, U3, W0, W1, W2, W3);
        DO_STAGE(H_PAIR, 3, U0, U2, U1, U3, W0, W2, W1, W3);  // pairs (0,2),(1,3)

        // ---- transpose 1 through the single slab, row0 then row1.
        // In-order DS pipe: U's b32 reads are issued (and complete) before
        // W's b128 writes touch the same words -> no barrier needed.
        *(f32x4*)(L + wb + 0)  = U0;
        *(f32x4*)(L + wb + 4)  = U1;
        *(f32x4*)(L + wb + 8)  = U2;
        *(f32x4*)(L + wb + 12) = U3;
        U0.x = L[rb + 0 * 20];  U0.y = L[rb + 1 * 20];  U0.z = L[rb + 2 * 20];  U0.w = L[rb + 3 * 20];
        U1.x = L[rb + 4 * 20];  U1.y = L[rb + 5 * 20];  U1.z = L[rb + 6 * 20];  U1.w = L[rb + 7 * 20];
        U2.x = L[rb + 8 * 20];  U2.y = L[rb + 9 * 20];  U2.z = L[rb + 10 * 20]; U2.w = L[rb + 11 * 20];
        U3.x = L[rb + 12 * 20]; U3.y = L[rb + 13 * 20]; U3.z = L[rb + 14 * 20]; U3.w = L[rb + 15 * 20];
        *(f32x4*)(L + wb + 0)  = W0;
        *(f32x4*)(L + wb + 4)  = W1;
        *(f32x4*)(L + wb + 8)  = W2;
        *(f32x4*)(L + wb + 12) = W3;
        W0.x = L[rb + 0 * 20];  W0.y = L[rb + 1 * 20];  W0.z = L[rb + 2 * 20];  W0.w = L[rb + 3 * 20];
        W1.x = L[rb + 4 * 20];  W1.y = L[rb + 5 * 20];  W1.z = L[rb + 6 * 20];  W1.w = L[rb + 7 * 20];
        W2.x = L[rb + 8 * 20];  W2.y = L[rb + 9 * 20];  W2.z = L[rb + 10 * 20]; W2.w = L[rb + 11 * 20];
        W3.x = L[rb + 12 * 20]; W3.y = L[rb + 13 * 20]; W3.z = L[rb + 14 * 20]; W3.w = L[rb + 15 * 20];

        // ---- stages 4-7 (layout B, in regs)
        DO_STAGE(H_EVEN, 4, U0, U1, U2, U3, W0, W1, W2, W3);
        DO_STAGE(H_ODD,  5, U0, U1, U2, U3, W0, W1, W2, W3);
        DO_STAGE(H_PAIR, 6, U0, U1, U2, U3, W0, W1, W2, W3);
        DO_STAGE(H_PAIR, 7, U0, U2, U1, U3, W0, W2, W1, W3);

        // ---- transpose 2 through the single slab, row0 then row1.
        L[rb + 0 * 20]  = U0.x; L[rb + 1 * 20]  = U0.y; L[rb + 2 * 20]  = U0.z; L[rb + 3 * 20]  = U0.w;
        L[rb + 4 * 20]  = U1.x; L[rb + 5 * 20]  = U1.y; L[rb + 6 * 20]  = U1.z; L[rb + 7 * 20]  = U1.w;
        L[rb + 8 * 20]  = U2.x; L[rb + 9 * 20]  = U2.y; L[rb + 10 * 20] = U2.z; L[rb + 11 * 20] = U2.w;
        L[rb + 12 * 20] = U3.x; L[rb + 13 * 20] = U3.y; L[rb + 14 * 20] = U3.z; L[rb + 15 * 20] = U3.w;
        U0 = *(const f32x4*)(L + cb);
        U1 = *(const f32x4*)(L + cb + 320);
        U2 = *(const f32x4*)(L + cb + 640);
        U3 = *(const f32x4*)(L + cb + 960);
        L[rb + 0 * 20]  = W0.x; L[rb + 1 * 20]  = W0.y; L[rb + 2 * 20]  = W0.z; L[rb + 3 * 20]  = W0.w;
        L[rb + 4 * 20]  = W1.x; L[rb + 5 * 20]  = W1.y; L[rb + 6 * 20]  = W1.z; L[rb + 7 * 20]  = W1.w;
        L[rb + 8 * 20]  = W2.x; L[rb + 9 * 20]  = W2.y; L[rb + 10 * 20] = W2.z; L[rb + 11 * 20] = W2.w;
        L[rb + 12 * 20] = W3.x; L[rb + 13 * 20] = W3.y; L[rb + 14 * 20] = W3.z; L[rb + 15 * 20] = W3.w;
        W0 = *(const f32x4*)(L + cb);
        W1 = *(const f32x4*)(L + cb + 320);
        W2 = *(const f32x4*)(L + cb + 640);
        W3 = *(const f32x4*)(L + cb + 960);

        // ---- stages 8-9 (layout C, in regs)
        DO_STAGE(H_PAIR, 8, U0, U1, U2, U3, W0, W1, W2, W3);
        DO_STAGE(H_PAIR, 9, U0, U2, U1, U3, W0, W2, W1, W3);

        float* o0 = out + (long long)r0 * BF_DIM;
        *(f32x4*)(o0 + lane * 4)       = U0;
        *(f32x4*)(o0 + 256 + lane * 4) = U1;
        *(f32x4*)(o0 + 512 + lane * 4) = U2;
        *(f32x4*)(o0 + 768 + lane * 4) = U3;
        if (has1) {
            float* o1 = out + (long long)r1 * BF_DIM;
            *(f32x4*)(o1 + lane * 4)       = W0;
            *(f32x4*)(o1 + 256 + lane * 4) = W1;
            *(f32x4*)(o1 + 512 + lane * 4) = W2;
            *(f32x4*)(o1 + 768 + lane * 4) = W3;
        }
    }
}

extern "C" void kernel_launch(void* const* d_in, const int* in_sizes, int n_in,
                              void* d_out, int out_size, void* d_ws, size_t ws_size,
                              hipStream_t stream) {
    const float* x      = (const float*)d_in[0];
    const float* angles = (const float*)d_in[1];
    float*       out    = (float*)d_out;
    unsigned*    cs     = (unsigned*)d_ws;  // 10*512*4 = 20480 bytes

    const int ncs = BF_STAGES * (BF_DIM / 2);
    bf_fill_cs<<<(ncs + 255) / 256, 256, 0, stream>>>(angles, cs, ncs);

    const int rows    = in_sizes[0] / BF_DIM;
    const int n_pairs = (rows + 1) / 2;
    int blocks = (n_pairs + 3) / 4;
    if (blocks > 2048) blocks = 2048;     // 8 blocks/CU (20KB LDS) -> 32 waves/CU
    const int pair_stride = blocks * 4;   // total waves
    bf_butterfly<<<blocks, 256, 0, stream>>>(x, (const f16x8*)cs, out, rows, pair_stride);
}